// Round 14
// baseline (240.246 us; speedup 1.0000x reference)
//
#include <hip/hip_runtime.h>
#include <math.h>

#define B_   32
#define T_   64
#define D_   300
#define H_   256
#define G4H  1024   // 4*H
#define M_   64
#define C_   5

typedef _Float16 h2v __attribute__((ext_vector_type(2)));
typedef _Float16 h8  __attribute__((ext_vector_type(8)));
typedef float    f4  __attribute__((ext_vector_type(4)));

__device__ __forceinline__ float sigmoidf_(float x) { return 1.0f / (1.0f + expf(-x)); }

__device__ __forceinline__ float dot2_(h2v a, h2v b, float c) {
#if __has_builtin(__builtin_amdgcn_fdot2)
    return __builtin_amdgcn_fdot2(a, b, c, false);
#else
    return c + (float)a[0] * (float)b[0] + (float)a[1] * (float)b[1];
#endif
}

// ---------------------------------------------------------------------------
// K0: zero exbuf (64*64*256 u32) + outf (64*512 f32) — write-once tag slots
// and the atomicAdd target must start clean every call (ws not re-poisoned).
// ---------------------------------------------------------------------------
__global__ void k_zero(unsigned* __restrict__ p, int n4) {
    int idx = blockIdx.x * blockDim.x + threadIdx.x;
    uint4 z = {0u, 0u, 0u, 0u};
    if (idx < n4) ((uint4*)p)[idx] = z;
}

// ---------------------------------------------------------------------------
// K1: length[b]. Coalesced: 16 lanes per t read 64B-contiguous segments.
// ---------------------------------------------------------------------------
__global__ void __launch_bounds__(1024)
k_length(const float* __restrict__ x, int* __restrict__ length) {
    const int b   = blockIdx.x;
    const int tid = threadIdx.x;
    const int t   = tid >> 4;        // 0..63
    const int j   = tid & 15;        // lane within 16-group

    __shared__ int cnt;
    if (tid == 0) cnt = 0;
    __syncthreads();

    const float* row = x + (size_t)(b * T_ + t) * D_;
    float mv = 0.f;
    #pragma unroll
    for (int i = 0; i < 19; ++i) {
        int d = j + 16 * i;
        if (d < D_) mv = fmaxf(mv, fabsf(row[d]));
    }
    #pragma unroll
    for (int off = 8; off >= 1; off >>= 1) mv = fmaxf(mv, __shfl_xor(mv, off));
    if (j == 0 && mv > 0.f) atomicAdd(&cnt, 1);
    __syncthreads();
    if (tid == 0) length[b] = cnt;
}

// ---------------------------------------------------------------------------
// K2: xw = x-part of gate pre-activations (+ bias). f16 MFMA GEMM.
// ---------------------------------------------------------------------------
__global__ void __launch_bounds__(256)
k_xw(const float* __restrict__ x,
     const float* __restrict__ Wfw, const float* __restrict__ bfw,
     const float* __restrict__ Wbw, const float* __restrict__ bbw,
     float* __restrict__ xw) {
    const int nt  = blockIdx.x;       // 0..15 col tile
    const int mt  = blockIdx.y;       // 0..15 row tile
    const int tid = threadIdx.x;      // 256
    const int w   = tid >> 6;         // wave 0..3
    const int l   = tid & 63;
    const int n0  = nt * 128, m0 = mt * 128;
    const int dir = n0 >> 10;               // 1024%128==0: tiles don't straddle
    const float* W    = dir ? Wbw : Wfw;
    const float* bias = dir ? bbw : bfw;
    const int ncol0 = n0 & 1023;

    __shared__ __align__(16) _Float16 As[128][40];  // 32 k + 8 pad
    __shared__ __align__(16) _Float16 Bs[128][40];  // [col][k]

    f4 acc[4][4];
    #pragma unroll
    for (int i = 0; i < 4; ++i)
        #pragma unroll
        for (int j = 0; j < 4; ++j) acc[i][j] = (f4){0.f, 0.f, 0.f, 0.f};

    const int wr = (w >> 1) * 64;   // wave row quadrant
    const int wc = (w & 1) * 64;    // wave col quadrant

    for (int k0 = 0; k0 < 320; k0 += 32) {
        // A: 128 rows x 32 k, float4 along k (D_=300 is 4-aligned)
        #pragma unroll
        for (int p = 0; p < 4; ++p) {
            int row = (tid >> 3) + p * 32;
            int kq  = tid & 7;
            int k   = k0 + kq * 4;
            f4 v = (k < D_) ? *(const f4*)&x[(size_t)(m0 + row) * D_ + k]
                            : (f4){0.f, 0.f, 0.f, 0.f};
            _Float16* dst = &As[row][kq * 4];
            dst[0] = (_Float16)v[0]; dst[1] = (_Float16)v[1];
            dst[2] = (_Float16)v[2]; dst[3] = (_Float16)v[3];
        }
        // B: 32 k x 128 cols, float4 along col
        #pragma unroll
        for (int p = 0; p < 4; ++p) {
            int kk   = (tid >> 5) + p * 8;
            int colq = tid & 31;
            int k    = k0 + kk;
            f4 v = (k < D_) ? *(const f4*)&W[(size_t)k * G4H + ncol0 + colq * 4]
                            : (f4){0.f, 0.f, 0.f, 0.f};
            #pragma unroll
            for (int i = 0; i < 4; ++i) Bs[colq * 4 + i][kk] = (_Float16)v[i];
        }
        __syncthreads();

        h8 afr[4], bfr[4];
        #pragma unroll
        for (int fr = 0; fr < 4; ++fr)
            afr[fr] = *(const h8*)&As[wr + fr * 16 + (l & 15)][(l >> 4) * 8];
        #pragma unroll
        for (int fc = 0; fc < 4; ++fc)
            bfr[fc] = *(const h8*)&Bs[wc + fc * 16 + (l & 15)][(l >> 4) * 8];
        #pragma unroll
        for (int fr = 0; fr < 4; ++fr)
            #pragma unroll
            for (int fc = 0; fc < 4; ++fc)
                acc[fr][fc] = __builtin_amdgcn_mfma_f32_16x16x32_f16(
                    afr[fr], bfr[fc], acc[fr][fc], 0, 0, 0);
        __syncthreads();
    }

    #pragma unroll
    for (int fc = 0; fc < 4; ++fc) {
        int col = ncol0 + wc + fc * 16 + (l & 15);
        float bv = bias[col];
        #pragma unroll
        for (int fr = 0; fr < 4; ++fr) {
            #pragma unroll
            for (int e = 0; e < 4; ++e) {
                int row = m0 + wr + fr * 16 + (l >> 4) * 4 + e;
                xw[(size_t)dir * 2048 * G4H + (size_t)row * G4H + col] =
                    acc[fr][fc][e] + bv;
            }
        }
    }
}

// ---------------------------------------------------------------------------
// K3: PRODUCER-CONSUMER fused kernel, 512 blocks x 512 threads (2 blocks/CU,
// all co-resident).
//   Blocks 0..255 (PRODUCER): the unfused round-7 LSTM recurrence — 64 groups
//   (dir,b) x 4 column-slices, W_h column-half in registers, fdot2 dot,
//   tagged-data h exchange. Publishes h into a 64-DEEP per-step exbuf slot
//   (write-once, tag = LSB 1, region zeroed per call) — no ring, no reuse,
//   no overwrite hazard. Producers never wait on consumers.
//   Blocks 256..511 (CONSUMER): (mg 0..7) x (b 0..31). Thread d polls the
//   per-step slot for its h word (read-only; skips masked steps where the
//   reference output is 0), streams ent[m,b,t,d] for 8 m's against it, and
//   atomicAdds the 8 register partials into outf at the end. The 268 MB ent
//   stream runs CONCURRENTLY with the recurrence on separate waves instead
//   of inside its serial step loop.
// ---------------------------------------------------------------------------
__global__ void __launch_bounds__(512)
k_main(const float* __restrict__ Wfw, const float* __restrict__ Wbw,
       const float* __restrict__ xw, const int* __restrict__ length,
       const float* __restrict__ ent, float* __restrict__ outf,
       unsigned* __restrict__ exbuf) {
    const int tid = threadIdx.x;

    if (blockIdx.x < 256) {
        // ======================= PRODUCER =======================
        const int bid = blockIdx.x;
        const int js  = bid >> 6;        // 0..3 column slice
        const int g   = bid & 63;        // group id
        const int dir = g >> 5;
        const int b   = g & 31;
        const int w   = tid >> 6;        // wave 0..7
        const int l   = tid & 63;
        const int c     = w * 32 + (l & 31);   // gate-col 0..255
        const int khalf = l >> 5;              // 0: k 0..127, 1: k 128..255
        const int colg  = (c >> 6) * 256 + js * 64 + (c & 63);

        __shared__ __align__(8) _Float16 hl_h[256];
        __shared__ float zfin[256];

        const float* Wg = dir ? Wbw : Wfw;

        h2v wreg[64];
        #pragma unroll
        for (int p = 0; p < 64; ++p) {
            int k = khalf * 128 + 2 * p;
            float w0 = Wg[(size_t)(D_ + k) * G4H + colg];
            float w1 = Wg[(size_t)(D_ + k + 1) * G4H + colg];
            h2v t; t[0] = (_Float16)w0; t[1] = (_Float16)w1;
            wreg[p] = t;
        }

        if (tid < 256) hl_h[tid] = (_Float16)0.f;
        const int len = length[b];
        const size_t xrow = (size_t)(dir * B_ + b) * T_;
        __syncthreads();

        float cst = 0.f, hprev = 0.f;

        for (int s = 0; s < T_; ++s) {
            const int tt = dir ? (T_ - 1 - s) : s;
            const size_t slotBase = ((size_t)g * 64 + s) * 256;  // per-step slot

            float xv = 0.f;
            if (l < 32) xv = xw[(xrow + tt) * G4H + colg];

            // dot: this col, this k-half: 32 broadcast b64 reads + 64 fdot2
            float acc = 0.f;
            const uint2* hp = (const uint2*)&hl_h[khalf * 128];
            #pragma unroll
            for (int j = 0; j < 32; ++j) {
                uint2 hv = hp[j];
                acc = dot2_(wreg[2 * j],     __builtin_bit_cast(h2v, hv.x), acc);
                acc = dot2_(wreg[2 * j + 1], __builtin_bit_cast(h2v, hv.y), acc);
            }
            acc += __shfl_xor(acc, 32);          // combine the two k-halves
            if (l < 32) zfin[c] = acc + xv;
            __syncthreads();

            // gates for this block's 64 h-columns; publish tagged h word
            if (tid < 64) {
                float zi = zfin[tid], zj = zfin[64 + tid];
                float zf = zfin[128 + tid], zo = zfin[192 + tid];
                float cn = sigmoidf_(zf + 1.0f) * cst + sigmoidf_(zi) * tanhf(zj);
                float hn = sigmoidf_(zo) * tanhf(cn);
                bool  msk = (tt < len);
                float hk2 = msk ? hn : hprev;
                if (msk) cst = cn;
                hprev = hk2;
                int jglob = js * 64 + tid;
                hl_h[jglob] = (_Float16)hk2;     // own slice straight into LDS
                unsigned bits = (__float_as_uint(hk2) & ~1u) | 1u;  // tag LSB=1
                __hip_atomic_store(&exbuf[slotBase + jglob], bits,
                                   __ATOMIC_RELAXED, __HIP_MEMORY_SCOPE_AGENT);
            }

            // poll peers' tagged words (write-once slot: tag==1 when ready)
            if (tid < 256 && (tid >> 6) != js) {
                unsigned v; unsigned it = 0;
                for (;;) {
                    v = __hip_atomic_load(&exbuf[slotBase + tid],
                                          __ATOMIC_RELAXED, __HIP_MEMORY_SCOPE_AGENT);
                    if (v & 1u) break;
                    __builtin_amdgcn_s_sleep(1);
                    if (++it > (1u << 22)) break;   // safety valve
                }
                hl_h[tid] = (_Float16)__uint_as_float(v);
            }
            __syncthreads();
        }
    } else {
        // ======================= CONSUMER =======================
        const int cid = blockIdx.x - 256;
        const int mg  = cid >> 5;        // 0..7
        const int b   = cid & 31;
        const int d   = tid;             // 0..511
        const int half = d >> 8;         // 0: fw (dir 0), 1: bw (dir 1)
        const int g    = half ? (32 + b) : b;
        const int col  = d & 255;
        const int len  = length[b];

        float acc[8] = {};

        for (int s = 0; s < T_; ++s) {
            const int t = half ? (T_ - 1 - s) : s;
            if (t >= len) continue;      // reference output is 0 here — skip

            const size_t slotBase = ((size_t)g * 64 + s) * 256;
            unsigned v; unsigned it = 0;
            for (;;) {
                v = __hip_atomic_load(&exbuf[slotBase + col],
                                      __ATOMIC_RELAXED, __HIP_MEMORY_SCOPE_AGENT);
                if (v & 1u) break;
                __builtin_amdgcn_s_sleep(1);
                if (++it > (1u << 22)) break;   // safety valve
            }
            float h = __uint_as_float(v);   // for t<len this is exactly h_out

            #pragma unroll
            for (int i = 0; i < 8; ++i)
                acc[i] += ent[(((size_t)(mg * 8 + i) * B_ + b) * T_ + t) * 512 + d] * h;
        }

        #pragma unroll
        for (int i = 0; i < 8; ++i)
            atomicAdd(&outf[(mg * 8 + i) * 512 + d], acc[i]);
    }
}

// ---------------------------------------------------------------------------
// K5: l1 = relu(outf/T @ W1 + b1)   (outf already summed over b via atomics)
// ---------------------------------------------------------------------------
__global__ void k_l1(const float* __restrict__ outf, const float* __restrict__ W1,
                     const float* __restrict__ b1, float* __restrict__ l1) {
    const int m = blockIdx.x;
    const int j = threadIdx.x;  // 0..255
    __shared__ float of[512];
    for (int d = j; d < 512; d += 256)
        of[d] = outf[(size_t)m * 512 + d] * (1.0f / T_);
    __syncthreads();
    float z = b1[j];
    for (int k = 0; k < 512; ++k) z += of[k] * W1[(size_t)k * H_ + j];
    l1[(size_t)m * H_ + j] = fmaxf(z, 0.f);
}

// ---------------------------------------------------------------------------
// K6: head + loss
// ---------------------------------------------------------------------------
__global__ void k_head(const float* __restrict__ l1, const float* __restrict__ W2,
                       const float* __restrict__ b2, const int* __restrict__ labels,
                       float* __restrict__ out) {
    const int tid = threadIdx.x;  // 320 threads
    __shared__ float red[320];
    float term = 0.f;
    if (tid < 320) {
        int m = tid / 5, cc = tid % 5;
        float z = b2[cc];
        for (int k = 0; k < H_; ++k) z += l1[(size_t)m * H_ + k] * W2[(size_t)k * C_ + cc];
        float p = 1.f / (1.f + expf(-z));
        out[tid] = p;
        term = -(float)labels[tid] * logf(p);
    }
    red[tid] = term;
    __syncthreads();
    if (tid == 0) {
        float s = 0.f;
        for (int i = 0; i < 320; ++i) s += red[i];
        out[320] = s / (float)C_;
    }
}

// ---------------------------------------------------------------------------
extern "C" void kernel_launch(void* const* d_in, const int* in_sizes, int n_in,
                              void* d_out, int out_size, void* d_ws, size_t ws_size,
                              hipStream_t stream) {
    const float* x      = (const float*)d_in[0];
    const float* ent    = (const float*)d_in[1];
    const int*   labels = (const int*)d_in[2];
    const float* Wfw    = (const float*)d_in[3];
    const float* bfw    = (const float*)d_in[4];
    const float* Wbw    = (const float*)d_in[5];
    const float* bbw    = (const float*)d_in[6];
    const float* W1     = (const float*)d_in[7];
    const float* b1     = (const float*)d_in[8];
    const float* W2     = (const float*)d_in[9];
    const float* b2     = (const float*)d_in[10];
    float* out = (float*)d_out;

    float*    ws     = (float*)d_ws;
    float*    xw     = ws;                            // 4,194,304 floats (16 MB)
    unsigned* exbuf  = (unsigned*)(xw + 4194304);     // 1,048,576 u32 (4 MB)
    float*    outf   = (float*)(exbuf + 1048576);     // 32,768 floats (128 KB)
    float*    l1     = outf + 32768;                  // 16,384 floats
    int*      length = (int*)(l1 + 16384);            // 32 ints

    // zero exbuf + outf (contiguous): (1048576 + 32768)/4 = 270,336 uint4
    const int n4 = 270336;
    k_zero<<<(n4 + 255) / 256, 256, 0, stream>>>(exbuf, n4);
    k_length<<<32, 1024, 0, stream>>>(x, length);
    k_xw<<<dim3(16, 16), 256, 0, stream>>>(x, Wfw, bfw, Wbw, bbw, xw);
    k_main<<<512, 512, 0, stream>>>(Wfw, Wbw, xw, length, ent, outf, exbuf);
    k_l1<<<64, 256, 0, stream>>>(outf, W1, b1, l1);
    k_head<<<1, 320, 0, stream>>>(l1, W2, b2, labels, out);
}

// Round 16
// 206.436 us; speedup vs baseline: 1.1638x; 1.1638x over previous
//
#include <hip/hip_runtime.h>
#include <math.h>

#define B_   32
#define T_   64
#define D_   300
#define H_   256
#define G4H  1024   // 4*H
#define M_   64
#define C_   5

typedef _Float16 h2v __attribute__((ext_vector_type(2)));
typedef _Float16 h8  __attribute__((ext_vector_type(8)));
typedef float    f4  __attribute__((ext_vector_type(4)));

__device__ __forceinline__ float sigmoidf_(float x) { return 1.0f / (1.0f + expf(-x)); }

__device__ __forceinline__ float dot2_(h2v a, h2v b, float c) {
#if __has_builtin(__builtin_amdgcn_fdot2)
    return __builtin_amdgcn_fdot2(a, b, c, false);
#else
    return c + (float)a[0] * (float)b[0] + (float)a[1] * (float)b[1];
#endif
}

// ---------------------------------------------------------------------------
// K1: length[b]. Coalesced: 16 lanes per t read 64B-contiguous segments.
// ---------------------------------------------------------------------------
__global__ void __launch_bounds__(1024)
k_length(const float* __restrict__ x, int* __restrict__ length) {
    const int b   = blockIdx.x;
    const int tid = threadIdx.x;
    const int t   = tid >> 4;        // 0..63
    const int j   = tid & 15;        // lane within 16-group

    __shared__ int cnt;
    if (tid == 0) cnt = 0;
    __syncthreads();

    const float* row = x + (size_t)(b * T_ + t) * D_;
    float mv = 0.f;
    #pragma unroll
    for (int i = 0; i < 19; ++i) {
        int d = j + 16 * i;
        if (d < D_) mv = fmaxf(mv, fabsf(row[d]));
    }
    #pragma unroll
    for (int off = 8; off >= 1; off >>= 1) mv = fmaxf(mv, __shfl_xor(mv, off));
    if (j == 0 && mv > 0.f) atomicAdd(&cnt, 1);
    __syncthreads();
    if (tid == 0) length[b] = cnt;
}

// ---------------------------------------------------------------------------
// K2: xw = x-part of gate pre-activations (+ bias). f16 MFMA GEMM.
// Staging vectorized: float4 global loads (4x fewer VMEM instructions).
// ---------------------------------------------------------------------------
__global__ void __launch_bounds__(256)
k_xw(const float* __restrict__ x,
     const float* __restrict__ Wfw, const float* __restrict__ bfw,
     const float* __restrict__ Wbw, const float* __restrict__ bbw,
     float* __restrict__ xw) {
    const int nt  = blockIdx.x;       // 0..15 col tile
    const int mt  = blockIdx.y;       // 0..15 row tile
    const int tid = threadIdx.x;      // 256
    const int w   = tid >> 6;         // wave 0..3
    const int l   = tid & 63;
    const int n0  = nt * 128, m0 = mt * 128;
    const int dir = n0 >> 10;               // 1024%128==0: tiles don't straddle
    const float* W    = dir ? Wbw : Wfw;
    const float* bias = dir ? bbw : bfw;
    const int ncol0 = n0 & 1023;

    __shared__ __align__(16) _Float16 As[128][40];  // 32 k + 8 pad
    __shared__ __align__(16) _Float16 Bs[128][40];  // [col][k]

    f4 acc[4][4];
    #pragma unroll
    for (int i = 0; i < 4; ++i)
        #pragma unroll
        for (int j = 0; j < 4; ++j) acc[i][j] = (f4){0.f, 0.f, 0.f, 0.f};

    const int wr = (w >> 1) * 64;   // wave row quadrant
    const int wc = (w & 1) * 64;    // wave col quadrant

    for (int k0 = 0; k0 < 320; k0 += 32) {
        // A: 128 rows x 32 k, float4 along k (D_=300 is 4-aligned: chunk all-in or all-out)
        #pragma unroll
        for (int p = 0; p < 4; ++p) {
            int row = (tid >> 3) + p * 32;
            int kq  = tid & 7;
            int k   = k0 + kq * 4;
            f4 v = (k < D_) ? *(const f4*)&x[(size_t)(m0 + row) * D_ + k]
                            : (f4){0.f, 0.f, 0.f, 0.f};
            _Float16* dst = &As[row][kq * 4];
            dst[0] = (_Float16)v[0]; dst[1] = (_Float16)v[1];
            dst[2] = (_Float16)v[2]; dst[3] = (_Float16)v[3];
        }
        // B: 32 k x 128 cols, float4 along col
        #pragma unroll
        for (int p = 0; p < 4; ++p) {
            int kk   = (tid >> 5) + p * 8;
            int colq = tid & 31;
            int k    = k0 + kk;
            f4 v = (k < D_) ? *(const f4*)&W[(size_t)k * G4H + ncol0 + colq * 4]
                            : (f4){0.f, 0.f, 0.f, 0.f};
            #pragma unroll
            for (int i = 0; i < 4; ++i) Bs[colq * 4 + i][kk] = (_Float16)v[i];
        }
        __syncthreads();

        h8 afr[4], bfr[4];
        #pragma unroll
        for (int fr = 0; fr < 4; ++fr)
            afr[fr] = *(const h8*)&As[wr + fr * 16 + (l & 15)][(l >> 4) * 8];
        #pragma unroll
        for (int fc = 0; fc < 4; ++fc)
            bfr[fc] = *(const h8*)&Bs[wc + fc * 16 + (l & 15)][(l >> 4) * 8];
        #pragma unroll
        for (int fr = 0; fr < 4; ++fr)
            #pragma unroll
            for (int fc = 0; fc < 4; ++fc)
                acc[fr][fc] = __builtin_amdgcn_mfma_f32_16x16x32_f16(
                    afr[fr], bfr[fc], acc[fr][fc], 0, 0, 0);
        __syncthreads();
    }

    #pragma unroll
    for (int fc = 0; fc < 4; ++fc) {
        int col = ncol0 + wc + fc * 16 + (l & 15);
        float bv = bias[col];
        #pragma unroll
        for (int fr = 0; fr < 4; ++fr) {
            #pragma unroll
            for (int e = 0; e < 4; ++e) {
                int row = m0 + wr + fr * 16 + (l >> 4) * 4 + e;
                xw[(size_t)dir * 2048 * G4H + (size_t)row * G4H + col] =
                    acc[fr][fc][e] + bv;
            }
        }
    }
}

// ---------------------------------------------------------------------------
// K3: LSTM recurrence + FUSED einsum (round-8 proven structure, measured
// best: 202 us total / 171 us k_lstm). 256 blocks = 64 groups (dir,b) x 4
// column-slices. W_h column-half in registers (64 h2v/thread, fdot2 dot,
// shfl_xor(32) combine). Cross-block h exchange: tagged-data protocol
// (fp32 LSB = ring-cycle parity, relaxed agent atomics, 4-slot ring).
// Einsum fusion: per step, every thread prefetches its 8 ent floats
// (m8 = tid>>3, d = js*64 + (tid&7)*8 ..+7) at loop top and MACs them
// against this block's masked h-slice (ho_l LDS) at loop bottom.
// lout is never materialized; partials written once at the end.
//
// Session post-mortem of refuted alternatives (rounds 9-15): nt-hints 216,
// f16-packed exchange 213, 2-chain interleave 302, producer/consumer split
// 240, stream double-buffer 208, LDS-only barriers 205, XCD-local sc0
// exchange HANG (stale-L2 poll; cross-CU visibility needs device scope).
// Conclusion: the recurrence is bound by the serial cross-CU publish->poll
// RTT (~1.3 us/step through L3, insensitive to traffic volume/prefetch/
// barrier semantics) — a dependency-chain latency floor, not a BW/FLOP
// roofline. This structure is the measured optimum.
// ---------------------------------------------------------------------------
__global__ void __launch_bounds__(512)
k_lstm(const float* __restrict__ Wfw, const float* __restrict__ Wbw,
       const float* __restrict__ xw, const int* __restrict__ length,
       const float* __restrict__ ent, float* __restrict__ partials,
       unsigned* __restrict__ exbuf) {
    const int bid = blockIdx.x;
    const int js  = bid >> 6;        // 0..3 column slice
    const int g   = bid & 63;        // group id
    const int dir = g >> 5;
    const int b   = g & 31;
    const int tid = threadIdx.x;     // 0..511
    const int w   = tid >> 6;        // wave 0..7
    const int l   = tid & 63;
    const int c     = w * 32 + (l & 31);   // gate-col 0..255 (gate = c>>6, jj = c&63)
    const int khalf = l >> 5;              // 0: k 0..127, 1: k 128..255
    const int colg  = (c >> 6) * 256 + js * 64 + (c & 63);
    const int m8  = tid >> 3;        // einsum m 0..63
    const int oct = tid & 7;         // einsum d-octet

    __shared__ __align__(8) _Float16 hl_h[256];
    __shared__ float zfin[256];
    __shared__ float ho_l[64];

    const float* Wg = dir ? Wbw : Wfw;

    // ---- stage this thread's W_h column-half into registers (f16 pairs) ----
    h2v wreg[64];
    #pragma unroll
    for (int p = 0; p < 64; ++p) {
        int k = khalf * 128 + 2 * p;
        float w0 = Wg[(size_t)(D_ + k) * G4H + colg];
        float w1 = Wg[(size_t)(D_ + k + 1) * G4H + colg];
        h2v t; t[0] = (_Float16)w0; t[1] = (_Float16)w1;
        wreg[p] = t;
    }

    if (tid < 256) hl_h[tid] = (_Float16)0.f;
    const int len = length[b];
    const size_t xrow = (size_t)(dir * B_ + b) * T_;
    // einsum base for this thread: ent[m8, b, t, dir*256 + js*64 + oct*8]
    const float* entp = ent + (((size_t)m8 * B_ + b) * T_) * 512
                            + dir * 256 + js * 64 + oct * 8;
    f4 accA = (f4){0.f, 0.f, 0.f, 0.f};
    f4 accB = (f4){0.f, 0.f, 0.f, 0.f};
    __syncthreads();

    float cst = 0.f, hprev = 0.f;

    for (int s = 0; s < T_; ++s) {
        const int tt = dir ? (T_ - 1 - s) : s;
        const unsigned tag = ((unsigned)(s >> 2) & 1u) ^ 1u;   // ring-cycle parity
        const size_t slotBase = ((size_t)g * 4 + (s & 3)) * 256;

        // prefetch einsum operands for this step (independent of recurrence)
        f4 e0 = *(const f4*)(entp + (size_t)tt * 512);
        f4 e1 = *(const f4*)(entp + (size_t)tt * 512 + 4);

        // x-part (issued early; consumed at zfin write)
        float xv = 0.f;
        if (l < 32) xv = xw[(xrow + tt) * G4H + colg];

        // ---- dot: this col, this k-half: 32 broadcast b64 reads + 64 fdot2 ----
        float acc = 0.f;
        const uint2* hp = (const uint2*)&hl_h[khalf * 128];
        #pragma unroll
        for (int j = 0; j < 32; ++j) {
            uint2 hv = hp[j];
            acc = dot2_(wreg[2 * j],     __builtin_bit_cast(h2v, hv.x), acc);
            acc = dot2_(wreg[2 * j + 1], __builtin_bit_cast(h2v, hv.y), acc);
        }
        acc += __shfl_xor(acc, 32);          // combine the two k-halves
        if (l < 32) zfin[c] = acc + xv;
        __syncthreads();

        // ---- gates for this block's 64 h-columns; publish tagged h slice ----
        if (tid < 64) {
            float zi = zfin[tid], zj = zfin[64 + tid], zf = zfin[128 + tid], zo = zfin[192 + tid];
            float cn = sigmoidf_(zf + 1.0f) * cst + sigmoidf_(zi) * tanhf(zj);
            float hn = sigmoidf_(zo) * tanhf(cn);
            bool  msk = (tt < len);
            float ho  = msk ? hn : 0.f;
            float hk2 = msk ? hn : hprev;
            if (msk) cst = cn;
            hprev = hk2;
            int jglob = js * 64 + tid;
            ho_l[tid] = ho;                  // masked output for fused einsum
            hl_h[jglob] = (_Float16)hk2;     // own slice straight into LDS
            unsigned bits = (__float_as_uint(hk2) & ~1u) | tag;
            __hip_atomic_store(&exbuf[slotBase + jglob], bits,
                               __ATOMIC_RELAXED, __HIP_MEMORY_SCOPE_AGENT);
        }

        // ---- poll peers' tagged words (single L3 trip, relaxed) ----
        if (tid < 256 && (tid >> 6) != js) {
            unsigned v; unsigned it = 0;
            for (;;) {
                v = __hip_atomic_load(&exbuf[slotBase + tid],
                                      __ATOMIC_RELAXED, __HIP_MEMORY_SCOPE_AGENT);
                if ((v & 1u) == tag) break;
                __builtin_amdgcn_s_sleep(1);
                if (++it > (1u << 20)) break;   // safety valve: wrong > wedged
            }
            hl_h[tid] = (_Float16)__uint_as_float(v);
        }
        __syncthreads();

        // ---- fused einsum MAC (ho_l stable until next gates, barrier-separated) ----
        #pragma unroll
        for (int i = 0; i < 4; ++i) {
            accA[i] += e0[i] * ho_l[oct * 8 + i];
            accB[i] += e1[i] * ho_l[oct * 8 + 4 + i];
        }
    }

    // ---- write partials: unique region per block: (m8, b, 64-d slice) ----
    float* pp = partials + ((size_t)m8 * B_ + b) * 512 + dir * 256 + js * 64 + oct * 8;
    *(f4*)pp = accA;
    *(f4*)(pp + 4) = accB;
}

// ---------------------------------------------------------------------------
// K5: reduce partials over b -> output_f, then l1 = relu(of @ W1 + b1)
// ---------------------------------------------------------------------------
__global__ void k_l1(const float* __restrict__ partials, const float* __restrict__ W1,
                     const float* __restrict__ b1, float* __restrict__ l1) {
    const int m = blockIdx.x;
    const int j = threadIdx.x;  // 0..255
    __shared__ float of[512];
    for (int d = j; d < 512; d += 256) {
        float s = 0.f;
        #pragma unroll
        for (int cc = 0; cc < 32; ++cc) s += partials[((size_t)m * B_ + cc) * 512 + d];
        of[d] = s * (1.0f / T_);
    }
    __syncthreads();
    float z = b1[j];
    for (int k = 0; k < 512; ++k) z += of[k] * W1[(size_t)k * H_ + j];
    l1[(size_t)m * H_ + j] = fmaxf(z, 0.f);
}

// ---------------------------------------------------------------------------
// K6: head + loss
// ---------------------------------------------------------------------------
__global__ void k_head(const float* __restrict__ l1, const float* __restrict__ W2,
                       const float* __restrict__ b2, const int* __restrict__ labels,
                       float* __restrict__ out) {
    const int tid = threadIdx.x;  // 320 threads
    __shared__ float red[320];
    float term = 0.f;
    if (tid < 320) {
        int m = tid / 5, cc = tid % 5;
        float z = b2[cc];
        for (int k = 0; k < H_; ++k) z += l1[(size_t)m * H_ + k] * W2[(size_t)k * C_ + cc];
        float p = 1.f / (1.f + expf(-z));
        out[tid] = p;
        term = -(float)labels[tid] * logf(p);
    }
    red[tid] = term;
    __syncthreads();
    if (tid == 0) {
        float s = 0.f;
        for (int i = 0; i < 320; ++i) s += red[i];
        out[320] = s / (float)C_;
    }
}

// ---------------------------------------------------------------------------
extern "C" void kernel_launch(void* const* d_in, const int* in_sizes, int n_in,
                              void* d_out, int out_size, void* d_ws, size_t ws_size,
                              hipStream_t stream) {
    const float* x      = (const float*)d_in[0];
    const float* ent    = (const float*)d_in[1];
    const int*   labels = (const int*)d_in[2];
    const float* Wfw    = (const float*)d_in[3];
    const float* bfw    = (const float*)d_in[4];
    const float* Wbw    = (const float*)d_in[5];
    const float* bbw    = (const float*)d_in[6];
    const float* W1     = (const float*)d_in[7];
    const float* b1     = (const float*)d_in[8];
    const float* W2     = (const float*)d_in[9];
    const float* b2     = (const float*)d_in[10];
    float* out = (float*)d_out;

    float*    ws       = (float*)d_ws;
    float*    xw       = ws;                            // 4,194,304 floats
    unsigned* exbuf    = (unsigned*)(xw + 4194304);     // 65,536 u32
    float*    l1       = (float*)(exbuf + 65536);       // 16,384 floats
    int*      length   = (int*)(l1 + 16384);            // 32 ints
    float*    partials = (float*)(length + 32);         // 1,048,576 floats

    k_length<<<32, 1024, 0, stream>>>(x, length);
    k_xw<<<dim3(16, 16), 256, 0, stream>>>(x, Wfw, bfw, Wbw, bbw, xw);
    k_lstm<<<256, 512, 0, stream>>>(Wfw, Wbw, xw, length, ent, partials, exbuf);
    k_l1<<<64, 256, 0, stream>>>(partials, W1, b1, l1);
    k_head<<<1, 320, 0, stream>>>(l1, W2, b2, labels, out);
}